// Round 4
// baseline (7843.633 us; speedup 1.0000x reference)
//
#include <hip/hip_runtime.h>
#include <hip/hip_bf16.h>
#include <stdint.h>

#define B_ 64
#define T_ 64
#define G_ 11
#define F_ 4
#define E_ 128
#define H_ 256
#define NG 1024
#define GT_ 704
#define LSEQ 11534336   // G*T*B*H elems per encoder layer

// weight blob region offsets (elements); L-copy of each buffer at +D* offset
#define OFF_WCAT0   0
#define OFF_WCAT123 393216
#define OFF_GCW0    1966080
#define OFF_GCW123  2490368
#define OFF_DWE     3276800
#define OFF_DWS     3407872
#define WBLOB_N     4194304
#define DW  ((size_t)WBLOB_N)     // weight blob lo-offset
#define DH4 ((size_t)46137344)    // hseq lo-offset (4*LSEQ)
#define DE  ((size_t)5767168)     // emb lo-offset
#define DAT ((size_t)16384)       // attn lo-offset
#define DH2 ((size_t)98304)       // h2buf lo-offset (2*192*256)

typedef __attribute__((ext_vector_type(8))) short bf16x8;
typedef __attribute__((ext_vector_type(4))) float f32x4;

__device__ __forceinline__ f32x4 mfma16(bf16x8 a, bf16x8 b, f32x4 c){
  return __builtin_amdgcn_mfma_f32_16x16x32_bf16(a, b, c, 0, 0, 0);
}
__device__ __forceinline__ float sigm(float x){ return 1.f/(1.f+__expf(-x)); }
__device__ __forceinline__ float tanh_(float x){ float e=__expf(2.f*x); return 1.f - 2.f/(e+1.f); }
__device__ __forceinline__ float b2f(__hip_bfloat16 v){ return __bfloat162float(v); }
__device__ __forceinline__ void splitw(float v, __hip_bfloat16* ph, __hip_bfloat16* pl){
  __hip_bfloat16 h = __float2bfloat16(v);
  *ph = h; *pl = __float2bfloat16(v - __bfloat162float(h));
}

// ---------------- weight conversion fp32 -> split bf16 (hi/lo blobs) -----------
__global__ void k_conv(const float* Wih0, const float* Wihs, const float* Whh,
                       const float* dWih0, const float* dWihs, const float* dWhh,
                       __hip_bfloat16* out)
{
  for (int i = blockIdx.x*blockDim.x + threadIdx.x; i < WBLOB_N; i += gridDim.x*blockDim.x){
    int j = i; float v;
    if (j < 393216) {                       // Wcat0 [1024][384] = [enc_Wih0 | enc_Whh0]
      int n = j/384, k = j%384;
      v = (k<128) ? Wih0[n*128+k] : Whh[n*256 + (k-128)];
    } else if ((j -= 393216) < 1572864) {   // Wcat123 3x[1024][512]
      int l = j/524288; int r = j%524288; int n = r/512, k = r%512;
      v = (k<256) ? Wihs[(l*1024+n)*256+k] : Whh[((l+1)*1024+n)*256 + (k-256)];
    } else if ((j -= 1572864) < 524288) {   // GcW0 [1024][512]
      int n = j/512, k = j%512;
      v = (k<256) ? dWih0[n*384+k] : dWhh[n*256 + (k-256)];
    } else if ((j -= 524288) < 786432) {    // GcW123 3x[1024][256]
      int l = j/262144; int r = j%262144; int n = r/256, k = r%256;
      v = dWhh[((l+1)*1024+n)*256+k];
    } else if ((j -= 786432) < 131072) {    // dWe [1024][128]
      int n = j/128, k = j%128;
      v = dWih0[n*384 + 256 + k];
    } else { j -= 131072; v = dWihs[j]; }   // dWs 3x[1024][256]
    splitw(v, out + i, out + i + DW);
  }
}

// ---------------- emb = relu(xg @ enc_lin_W^T + b), split bf16 ------------------
__global__ void k_emb(const float* x, const float* W, const float* bb, __hip_bfloat16* emb)
{
  const int N = G_*T_*B_*E_;
  for (int i = blockIdx.x*blockDim.x + threadIdx.x; i < N; i += gridDim.x*blockDim.x){
    int e = i & 127; int row = i >> 7;
    int b = row & 63; int t = (row >> 6) & 63; int g = row >> 12;
    const float* xp = x + ((size_t)(b*T_ + t)*G_ + g)*F_;
    float s = bb[e];
#pragma unroll
    for (int f = 0; f < 4; ++f) s += xp[f]*W[e*4+f];
    splitw(fmaxf(s, 0.f), emb + i, emb + i + DE);
  }
}

// ---------------- encoder wavefront step: (l, t=w-l) for all g ------------------
__global__ __launch_bounds__(256) void k_enc(
  __hip_bfloat16* hseq, const __hip_bfloat16* emb, float* cbuf,
  const __hip_bfloat16* wb, const float* bih, const float* bhh, int w)
{
  const int bid = blockIdx.x;
  const int l = bid / 44; const int rem = bid % 44;
  const int g = rem >> 2; const int hc = rem & 3;
  const int t = w - l;
  if (t < 0 || t >= T_) return;

  const int tid = threadIdx.x;
  const int wv = tid >> 6, lane = tid & 63;
  const int rowblk = (wv & 1) * 32;
  const int colblk = (wv >> 1) * 128;
  const int lm = lane & 15, lk = (lane >> 4) * 8;

  const __hip_bfloat16* xin; int xstride, K1, wstride; size_t DA;
  const __hip_bfloat16* W;
  if (l == 0){ xin = emb + (size_t)(g*T_ + t)*B_*E_; xstride = E_; K1 = E_; DA = DE;
               W = wb + OFF_WCAT0; wstride = 384; }
  else { xin = hseq + (size_t)(l-1)*LSEQ + (size_t)(g*T_ + t)*B_*H_; xstride = H_; K1 = H_; DA = DH4;
         W = wb + OFF_WCAT123 + (size_t)(l-1)*1024*512; wstride = 512; }
  const __hip_bfloat16* hprev = hseq + (size_t)l*LSEQ + ((size_t)g*T_ + (size_t)(t-1))*B_*H_;

  const __hip_bfloat16* ap0 = xin + (size_t)(rowblk + lm)*xstride + lk;
  const __hip_bfloat16* ap1 = xin + (size_t)(rowblk + 16 + lm)*xstride + lk;
  const __hip_bfloat16* hp0 = hprev + (size_t)(rowblk + lm)*H_ + lk;
  const __hip_bfloat16* hp1 = hprev + (size_t)(rowblk + 16 + lm)*H_ + lk;
  const __hip_bfloat16* wp[8];
#pragma unroll
  for (int cb = 0; cb < 8; ++cb){
    int v0 = colblk + cb*16 + lm;
    int n = (v0 >> 6)*256 + hc*64 + (v0 & 63);
    wp[cb] = W + (size_t)n*wstride + lk;
  }

  f32x4 acc[2][8];
#pragma unroll
  for (int i = 0; i < 2; ++i)
#pragma unroll
    for (int cb = 0; cb < 8; ++cb) acc[i][cb] = (f32x4)0.f;

  for (int ka = 0; ka < K1; ka += 32){
    bf16x8 a0h = *(const bf16x8*)(ap0 + ka);
    bf16x8 a0l = *(const bf16x8*)(ap0 + ka + DA);
    bf16x8 a1h = *(const bf16x8*)(ap1 + ka);
    bf16x8 a1l = *(const bf16x8*)(ap1 + ka + DA);
#pragma unroll
    for (int cb = 0; cb < 8; ++cb){
      bf16x8 bh = *(const bf16x8*)(wp[cb] + ka);
      bf16x8 bl = *(const bf16x8*)(wp[cb] + ka + DW);
      acc[0][cb] = mfma16(a0h, bh, acc[0][cb]);
      acc[0][cb] = mfma16(a0h, bl, acc[0][cb]);
      acc[0][cb] = mfma16(a0l, bh, acc[0][cb]);
      acc[1][cb] = mfma16(a1h, bh, acc[1][cb]);
      acc[1][cb] = mfma16(a1h, bl, acc[1][cb]);
      acc[1][cb] = mfma16(a1l, bh, acc[1][cb]);
    }
  }
  if (t > 0){
    for (int kh = 0; kh < H_; kh += 32){
      bf16x8 a0h = *(const bf16x8*)(hp0 + kh);
      bf16x8 a0l = *(const bf16x8*)(hp0 + kh + DH4);
      bf16x8 a1h = *(const bf16x8*)(hp1 + kh);
      bf16x8 a1l = *(const bf16x8*)(hp1 + kh + DH4);
#pragma unroll
      for (int cb = 0; cb < 8; ++cb){
        bf16x8 bh = *(const bf16x8*)(wp[cb] + K1 + kh);
        bf16x8 bl = *(const bf16x8*)(wp[cb] + K1 + kh + DW);
        acc[0][cb] = mfma16(a0h, bh, acc[0][cb]);
        acc[0][cb] = mfma16(a0h, bl, acc[0][cb]);
        acc[0][cb] = mfma16(a0l, bh, acc[0][cb]);
        acc[1][cb] = mfma16(a1h, bh, acc[1][cb]);
        acc[1][cb] = mfma16(a1h, bl, acc[1][cb]);
        acc[1][cb] = mfma16(a1l, bh, acc[1][cb]);
      }
    }
  }

  __shared__ float glds[64][256];
#pragma unroll
  for (int i = 0; i < 2; ++i)
#pragma unroll
    for (int cb = 0; cb < 8; ++cb){
      int row = rowblk + i*16 + (lane >> 4)*4;
      int col = colblk + cb*16 + lm;
#pragma unroll
      for (int r = 0; r < 4; ++r) glds[row + r][col] = acc[i][cb][r];
    }
  __syncthreads();

  float* cbp = cbuf + ((size_t)l*G_ + g)*B_*H_;
  __hip_bfloat16* hout = hseq + (size_t)l*LSEQ + (size_t)(g*T_ + t)*B_*H_;
  const float* bi = bih + l*NG; const float* bh = bhh + l*NG;
  for (int e = tid; e < 64*64; e += 256){
    int m = e >> 6, c = e & 63;
    int hcol = hc*64 + c;
    float gi = glds[m][c]       + bi[0*256+hcol] + bh[0*256+hcol];
    float gf = glds[m][64 + c]  + bi[1*256+hcol] + bh[1*256+hcol];
    float gg = glds[m][128 + c] + bi[2*256+hcol] + bh[2*256+hcol];
    float go = glds[m][192 + c] + bi[3*256+hcol] + bh[3*256+hcol];
    float cp = (t > 0) ? cbp[m*H_ + hcol] : 0.f;
    float c2 = sigm(gf)*cp + sigm(gi)*tanh_(gg);
    float h2 = sigm(go)*tanh_(c2);
    cbp[m*H_ + hcol] = c2;
    splitw(h2, hout + m*H_ + hcol, hout + DH4 + m*H_ + hcol);
  }
}

// ---------------- attention (hq.wa_h and attn_b cancel in softmax) --------------
__global__ __launch_bounds__(256) void k_attn(
  const __hip_bfloat16* hseq, const float* attnW, __hip_bfloat16* attn_bf)
{
  const int b = blockIdx.x; const int tid = threadIdx.x;
  const __hip_bfloat16* enc = hseq + (size_t)3*LSEQ;  // [gt][b][h]
  const float* wa_e = attnW + 256;
  __shared__ float sw[GT_];
  __shared__ float red[256];

  for (int it = 0; it < (GT_*4)/256; ++it){
    int idx = tid + it*256;
    int gt = idx >> 2, p = idx & 3;
    const __hip_bfloat16* ep = enc + ((size_t)gt*B_ + b)*H_ + p*64;
    float s = 0.f;
    for (int h = 0; h < 64; ++h) s += (b2f(ep[h]) + b2f(ep[h + DH4])) * wa_e[p*64 + h];
    s += __shfl_xor(s, 1);
    s += __shfl_xor(s, 2);
    if (p == 0) sw[gt] = s;
  }
  __syncthreads();
  float lmax = -1e30f;
  for (int idx = tid; idx < GT_; idx += 256) lmax = fmaxf(lmax, sw[idx]);
  red[tid] = lmax; __syncthreads();
  for (int s2 = 128; s2 > 0; s2 >>= 1){ if (tid < s2) red[tid] = fmaxf(red[tid], red[tid+s2]); __syncthreads(); }
  float M = red[0]; __syncthreads();
  float lsum = 0.f;
  for (int idx = tid; idx < GT_; idx += 256) lsum += __expf(sw[idx] - M);
  red[tid] = lsum; __syncthreads();
  for (int s2 = 128; s2 > 0; s2 >>= 1){ if (tid < s2) red[tid] += red[tid+s2]; __syncthreads(); }
  float Z = red[0]; __syncthreads();
  for (int idx = tid; idx < GT_; idx += 256) sw[idx] = __expf(sw[idx] - M) / Z;
  __syncthreads();
  float acc = 0.f;
  const __hip_bfloat16* ep = enc + (size_t)b*H_ + tid;
  for (int gt = 0; gt < GT_; ++gt){
    size_t o = (size_t)gt*B_*H_;
    acc += sw[gt] * (b2f(ep[o]) + b2f(ep[o + DH4]));
  }
  splitw(acc, attn_bf + b*H_ + tid, attn_bf + DAT + b*H_ + tid);
}

// ---------------- Gc[l][b][1024] = const gate part of decoder cells -------------
__global__ __launch_bounds__(256) void k_gc(
  const __hip_bfloat16* hseq, const __hip_bfloat16* attn_bf,
  const __hip_bfloat16* wb, const float* dbih, const float* dbhh,
  const int* p_to, float* Gc)
{
  const int to = *p_to;
  const int l = blockIdx.x >> 2, cb4 = blockIdx.x & 3;
  const int tid = threadIdx.x, wv = tid >> 6, lane = tid & 63;
  const int rowblk = (wv & 1)*32, colblk = (wv >> 1)*128;
  const int lm = lane & 15, lk = (lane >> 4)*8;
  const __hip_bfloat16* dech = hseq + (size_t)l*LSEQ + ((size_t)to*T_ + 63)*B_*H_;
  const __hip_bfloat16* W; int wstride;
  if (l == 0){ W = wb + OFF_GCW0; wstride = 512; }
  else { W = wb + OFF_GCW123 + (size_t)(l-1)*1024*256; wstride = 256; }
  const __hip_bfloat16* wp[8];
#pragma unroll
  for (int cb = 0; cb < 8; ++cb){
    int n = cb4*256 + colblk + cb*16 + lm;
    wp[cb] = W + (size_t)n*wstride + lk;
  }
  f32x4 acc[2][8];
#pragma unroll
  for (int i = 0; i < 2; ++i)
#pragma unroll
    for (int cb = 0; cb < 8; ++cb) acc[i][cb] = (f32x4)0.f;

  if (l == 0){
    const __hip_bfloat16* a0p = attn_bf + (size_t)(rowblk + lm)*H_ + lk;
    const __hip_bfloat16* a1p = attn_bf + (size_t)(rowblk + 16 + lm)*H_ + lk;
    for (int ka = 0; ka < 256; ka += 32){
      bf16x8 a0h = *(const bf16x8*)(a0p + ka);
      bf16x8 a0l = *(const bf16x8*)(a0p + ka + DAT);
      bf16x8 a1h = *(const bf16x8*)(a1p + ka);
      bf16x8 a1l = *(const bf16x8*)(a1p + ka + DAT);
#pragma unroll
      for (int cb = 0; cb < 8; ++cb){
        bf16x8 bh = *(const bf16x8*)(wp[cb] + ka);
        bf16x8 bl = *(const bf16x8*)(wp[cb] + ka + DW);
        acc[0][cb] = mfma16(a0h, bh, acc[0][cb]);
        acc[0][cb] = mfma16(a0h, bl, acc[0][cb]);
        acc[0][cb] = mfma16(a0l, bh, acc[0][cb]);
        acc[1][cb] = mfma16(a1h, bh, acc[1][cb]);
        acc[1][cb] = mfma16(a1h, bl, acc[1][cb]);
        acc[1][cb] = mfma16(a1l, bh, acc[1][cb]);
      }
    }
  }
  const int koff = (l == 0) ? 256 : 0;
  const __hip_bfloat16* h0p = dech + (size_t)(rowblk + lm)*H_ + lk;
  const __hip_bfloat16* h1p = dech + (size_t)(rowblk + 16 + lm)*H_ + lk;
  for (int ka = 0; ka < 256; ka += 32){
    bf16x8 a0h = *(const bf16x8*)(h0p + ka);
    bf16x8 a0l = *(const bf16x8*)(h0p + ka + DH4);
    bf16x8 a1h = *(const bf16x8*)(h1p + ka);
    bf16x8 a1l = *(const bf16x8*)(h1p + ka + DH4);
#pragma unroll
    for (int cb = 0; cb < 8; ++cb){
      bf16x8 bh = *(const bf16x8*)(wp[cb] + koff + ka);
      bf16x8 bl = *(const bf16x8*)(wp[cb] + koff + ka + DW);
      acc[0][cb] = mfma16(a0h, bh, acc[0][cb]);
      acc[0][cb] = mfma16(a0h, bl, acc[0][cb]);
      acc[0][cb] = mfma16(a0l, bh, acc[0][cb]);
      acc[1][cb] = mfma16(a1h, bh, acc[1][cb]);
      acc[1][cb] = mfma16(a1h, bl, acc[1][cb]);
      acc[1][cb] = mfma16(a1l, bh, acc[1][cb]);
    }
  }
#pragma unroll
  for (int i = 0; i < 2; ++i)
#pragma unroll
    for (int cb = 0; cb < 8; ++cb){
      int row = rowblk + i*16 + (lane >> 4)*4;
      int n = cb4*256 + colblk + cb*16 + lm;
#pragma unroll
      for (int r = 0; r < 4; ++r)
        Gc[((size_t)l*64 + (row + r))*NG + n] = acc[i][cb][r] + dbih[l*NG + n] + dbhh[l*NG + n];
    }
}

// ---------------- persistent decoder: 64 steps x 4 stages, flag-group sync ------
__global__ __launch_bounds__(256) void k_dec(
  const float* x, const float* cbuf, const float* Gc, const __hip_bfloat16* wb,
  const float* dembW, const float* dembB,
  const float* outW, const float* outB,
  __hip_bfloat16* h2buf, float* dout, unsigned int* flags, const int* p_to)
{
  const int to = *p_to;
  const int rt = blockIdx.x >> 2, hc = blockIdx.x & 3;
  const int j = rt >> 2, b0 = (rt & 3)*16;
  const int R0 = rt*16;
  const int tid = threadIdx.x, wv = tid >> 6, lane = tid & 63;
  const int lm = lane & 15, lk = (lane >> 4)*8;

  __shared__ float glds[16][256];
  __shared__ __hip_bfloat16 eldsH[16][136];
  __shared__ __hip_bfloat16 eldsL[16][136];
  __shared__ float outlds[16][4];
  unsigned int done = 0;

  for (int t = 0; t <= T_; ++t){
    if (tid < 64){
      int m = tid >> 2, f = tid & 3;
      int b = b0 + m;
      float s;
      if (t == 0){
        s = x[((size_t)(b*T_ + 63)*G_ + (to + j))*F_ + f];
      } else {
        const __hip_bfloat16* hp = h2buf + (size_t)1*192*H_ + (size_t)(R0 + m)*H_;
        s = outB[f];
        for (int h = 0; h < H_; ++h) s += (b2f(hp[h]) + b2f(hp[h + DH2])) * outW[f*H_ + h];
        if (hc == 0) dout[(((size_t)b*T_ + (t-1))*3 + j)*F_ + f] = s;
      }
      if (t < T_) outlds[m][f] = s;
    }
    if (t == T_) break;
    __syncthreads();
    for (int idx = tid; idx < 16*E_; idx += 256){
      int m = idx >> 7, ec = idx & 127;
      float s = dembB[ec];
#pragma unroll
      for (int f = 0; f < 4; ++f) s += outlds[m][f]*dembW[ec*4 + f];
      float e = fmaxf(s, 0.f);
      __hip_bfloat16 eh = __float2bfloat16(e);
      eldsH[m][ec] = eh;
      eldsL[m][ec] = __float2bfloat16(e - b2f(eh));
    }
    __syncthreads();

    for (int l = 0; l < 4; ++l){
      const __hip_bfloat16* W; int wstride, Kt;
      if (l == 0){ W = wb + OFF_DWE; wstride = E_; Kt = E_; }
      else { W = wb + OFF_DWS + (size_t)(l-1)*1024*256; wstride = H_; Kt = H_; }
      const __hip_bfloat16* aptr = nullptr;
      if (l > 0){
        int rb = (l - 1) & 1;
        aptr = h2buf + (size_t)rb*192*H_ + (size_t)(R0 + lm)*H_ + lk;
      }
      const __hip_bfloat16* wp[4];
#pragma unroll
      for (int cb = 0; cb < 4; ++cb){
        int n = wv*256 + hc*64 + cb*16 + lm;
        wp[cb] = W + (size_t)n*wstride + lk;
      }
      f32x4 acc[4];
#pragma unroll
      for (int cb = 0; cb < 4; ++cb) acc[cb] = (f32x4)0.f;
      for (int ka = 0; ka < Kt; ka += 32){
        bf16x8 ah, al;
        if (l == 0){ ah = *(const bf16x8*)(&eldsH[lm][ka + lk]);
                     al = *(const bf16x8*)(&eldsL[lm][ka + lk]); }
        else { ah = *(const bf16x8*)(aptr + ka);
               al = *(const bf16x8*)(aptr + ka + DH2); }
#pragma unroll
        for (int cb = 0; cb < 4; ++cb){
          bf16x8 bh = *(const bf16x8*)(wp[cb] + ka);
          bf16x8 bl = *(const bf16x8*)(wp[cb] + ka + DW);
          acc[cb] = mfma16(ah, bh, acc[cb]);
          acc[cb] = mfma16(ah, bl, acc[cb]);
          acc[cb] = mfma16(al, bh, acc[cb]);
        }
      }
#pragma unroll
      for (int cb = 0; cb < 4; ++cb){
        int row = (lane >> 4)*4, col = wv*64 + cb*16 + lm;
#pragma unroll
        for (int r = 0; r < 4; ++r) glds[row + r][col] = acc[cb][r];
      }
      __syncthreads();

      int wb2 = l & 1;
      __hip_bfloat16* hout = h2buf + (size_t)wb2*192*H_;
      const float* cf = cbuf + ((size_t)l*G_ + to)*B_*H_;
      const float* gcl = Gc + (size_t)l*64*NG;
      for (int idx = tid; idx < 16*64; idx += 256){
        int m = idx >> 6, c = idx & 63;
        int hcol = hc*64 + c; int b = b0 + m;
        float gi = glds[m][c]       + gcl[b*NG + 0*256 + hcol];
        float gf = glds[m][64 + c]  + gcl[b*NG + 1*256 + hcol];
        float gg = glds[m][128 + c] + gcl[b*NG + 2*256 + hcol];
        float go = glds[m][192 + c] + gcl[b*NG + 3*256 + hcol];
        float cp = cf[b*H_ + hcol];
        float c2 = sigm(gf)*cp + sigm(gi)*tanh_(gg);
        float h2v = sigm(go)*tanh_(c2);
        size_t oo = (size_t)(R0 + m)*H_ + hcol;
        __hip_bfloat16 hh = __float2bfloat16(h2v);
        hout[oo] = hh;
        hout[oo + DH2] = __float2bfloat16(h2v - b2f(hh));
      }
      __threadfence();
      __syncthreads();
      done++;
      if (tid == 0){
        __hip_atomic_fetch_add(&flags[rt], 1u, __ATOMIC_RELEASE, __HIP_MEMORY_SCOPE_AGENT);
        while (__hip_atomic_load(&flags[rt], __ATOMIC_ACQUIRE, __HIP_MEMORY_SCOPE_AGENT) < 4u*done)
          __builtin_amdgcn_s_sleep(1);
      }
      __syncthreads();
    }
  }
}

extern "C" void kernel_launch(void* const* d_in, const int* in_sizes, int n_in,
                              void* d_out, int out_size, void* d_ws, size_t ws_size,
                              hipStream_t stream)
{
  const float* x         = (const float*)d_in[0];
  const float* enc_lin_W = (const float*)d_in[2];
  const float* enc_lin_b = (const float*)d_in[3];
  const float* enc_Wih0  = (const float*)d_in[4];
  const float* enc_Wihs  = (const float*)d_in[5];
  const float* enc_Whh   = (const float*)d_in[6];
  const float* enc_bih   = (const float*)d_in[7];
  const float* enc_bhh   = (const float*)d_in[8];
  const float* dec_emb_W = (const float*)d_in[9];
  const float* dec_emb_b = (const float*)d_in[10];
  const float* attn_W    = (const float*)d_in[11];
  const float* dec_Wih0  = (const float*)d_in[13];
  const float* dec_Wihs  = (const float*)d_in[14];
  const float* dec_Whh   = (const float*)d_in[15];
  const float* dec_bih   = (const float*)d_in[16];
  const float* dec_bhh   = (const float*)d_in[17];
  const float* out_W     = (const float*)d_in[18];
  const float* out_b     = (const float*)d_in[19];
  const int*   p_to      = (const int*)d_in[20];
  float* dout = (float*)d_out;
  (void)in_sizes; (void)n_in; (void)out_size; (void)ws_size;

  char* ws = (char*)d_ws;
  size_t off = 0;
  auto take = [&](size_t nbytes) -> void* {
    void* p = ws + off; off += (nbytes + 255) & ~(size_t)255; return p; };
  __hip_bfloat16* hseq    = (__hip_bfloat16*)take((size_t)8*LSEQ*2);          // H+L
  __hip_bfloat16* emb     = (__hip_bfloat16*)take((size_t)2*G_*T_*B_*E_*2);   // H+L
  float*          cbuf    = (float*)take((size_t)4*G_*B_*H_*4);
  __hip_bfloat16* wblob   = (__hip_bfloat16*)take((size_t)2*WBLOB_N*2);       // H+L
  __hip_bfloat16* attn_bf = (__hip_bfloat16*)take((size_t)2*64*256*2);        // H+L
  float*          Gc      = (float*)take((size_t)4*64*1024*4);
  __hip_bfloat16* h2buf   = (__hip_bfloat16*)take((size_t)2*2*192*256*2);     // H+L
  unsigned int*   flags   = (unsigned int*)take(256);

  hipMemsetAsync(flags, 0, 256, stream);
  k_conv<<<2048, 256, 0, stream>>>(enc_Wih0, enc_Wihs, enc_Whh, dec_Wih0, dec_Wihs, dec_Whh, wblob);
  k_emb<<<2048, 256, 0, stream>>>(x, enc_lin_W, enc_lin_b, emb);
  for (int w = 0; w < 67; ++w)
    k_enc<<<176, 256, 0, stream>>>(hseq, emb, cbuf, wblob, enc_bih, enc_bhh, w);
  k_attn<<<64, 256, 0, stream>>>(hseq, attn_W, attn_bf);
  k_gc<<<16, 256, 0, stream>>>(hseq, attn_bf, wblob, dec_bih, dec_bhh, p_to, Gc);
  k_dec<<<48, 256, 0, stream>>>(x, cbuf, Gc, wblob, dec_emb_W, dec_emb_b, out_W, out_b,
                                h2buf, dout, flags, p_to);
}